// Round 1
// baseline (618.783 us; speedup 1.0000x reference)
//
#include <hip/hip_runtime.h>
#include <hip/hip_bf16.h>
#include <cstddef>
#include <cstdint>

// Problem constants (from setup_inputs): B=2, C=128, N=32768, K=9, H=512
#define BB 2
#define CC 128
#define NN 32768
#define KNBR 9
#define HH 512
#define PP (BB * NN)          // 65536 points
#define TWO_C (2 * CC)        // 256
#define EPSBN 1e-5f

// ---------------------------------------------------------------------------
// Transpose x [B, C, N] -> xT [B*N, C]
// tile: 32 n x 128 c per block, LDS padded to kill bank conflicts
__global__ __launch_bounds__(256) void transpose_kernel(
    const float* __restrict__ x, float* __restrict__ xT) {
    __shared__ float t[32][129];
    const int b = blockIdx.y;
    const int n0 = blockIdx.x * 32;
    const int tid = threadIdx.x;

    // read: consecutive threads -> consecutive n (coalesced along N)
    {
        const int tn = tid % 32;
        const int cq = tid / 32;          // 8 channel-passes
        for (int c = cq; c < CC; c += 8)
            t[tn][c] = x[((size_t)b * CC + c) * NN + n0 + tn];
    }
    __syncthreads();
    // write: consecutive threads -> consecutive c (coalesced along C)
    {
        const int ct = tid % 128;
        const int nq = tid / 128;         // 2 rows per pass
        for (int nl = nq; nl < 32; nl += 2)
            xT[((size_t)b * NN + n0 + nl) * CC + ct] = t[nl][ct];
    }
}

// ---------------------------------------------------------------------------
// Gather + max-relative + interleaved feature build.
// featT[p][2c] = x[p][c]; featT[p][2c+1] = max_k( x[e0[k]][c] - x[e1[k]][c] )
// 2 points per 256-thread block; 128 lanes (=channels) per point.
__global__ __launch_bounds__(256) void gather_kernel(
    const float* __restrict__ xT, const int* __restrict__ ei,
    float2* __restrict__ featT) {
    const int pt = blockIdx.x * 2 + (threadIdx.x >> 7);   // global point
    const int c  = threadIdx.x & 127;
    const int b  = pt >> 15;          // / NN
    const int n  = pt & (NN - 1);

    const float* xb = xT + (size_t)b * NN * CC;
    // edge_index layout [2, B, N, K]
    const int* e0 = ei + (((size_t)(0 * BB + b) * NN + n) * KNBR); // x_j (neighbor)
    const int* e1 = ei + (((size_t)(1 * BB + b) * NN + n) * KNBR); // x_i (center)

    const float xv = xb[(size_t)n * CC + c];
    float m = -INFINITY;
#pragma unroll
    for (int k = 0; k < KNBR; k++) {
        const int j0 = e0[k];
        const int j1 = e1[k];
        m = fmaxf(m, xb[(size_t)j0 * CC + c] - xb[(size_t)j1 * CC + c]);
    }
    featT[(size_t)pt * CC + c] = make_float2(xv, m);
}

// ---------------------------------------------------------------------------
// Tiled fp32 GEMM: Cout[p,o] = sum_k actA(A[p,k]) * W[o,k] + bias[o]
// actA(v) = ACT ? relu(act[k]*v + act[KTOT+k]) : v     (per-channel BN+ReLU)
// Block tile 64x64, 256 threads (16x16), 4x4 per thread, K-step 16.
template <int KTOT, bool ACT>
__global__ __launch_bounds__(256) void gemm_kernel(
    const float* __restrict__ A,    // [P, KTOT]
    const float* __restrict__ W,    // [OC, KTOT] row-major
    const float* __restrict__ bias, // [OC]
    const float* __restrict__ act,  // [2*KTOT] (a, then b) or unused
    float* __restrict__ Cout,       // [P, OC]
    int OC) {
    constexpr int KT = 16;
    __shared__ float As[KT][65];   // [kk][row]
    __shared__ float Ws[KT][65];   // [kk][col]

    const int pb = blockIdx.x * 64;
    const int ob = blockIdx.y * 64;
    const int tid = threadIdx.x;
    const int tx = tid & 15;       // -> output col group
    const int ty = tid >> 4;       // -> output row group
    const int lk = tid & 15;       // staging: k index
    const int lr = tid >> 4;       // staging: row/col base

    float acc[4][4] = {};

    for (int k0 = 0; k0 < KTOT; k0 += KT) {
        float aa = 0.f, ab = 0.f;
        if (ACT) { aa = act[k0 + lk]; ab = act[KTOT + k0 + lk]; }
#pragma unroll
        for (int i = 0; i < 4; i++) {
            const int r = lr + i * 16;
            float v = A[(size_t)(pb + r) * KTOT + k0 + lk];
            if (ACT) v = fmaxf(fmaf(aa, v, ab), 0.f);
            As[lk][r] = v;
        }
#pragma unroll
        for (int i = 0; i < 4; i++) {
            const int cidx = lr + i * 16;
            Ws[lk][cidx] = W[(size_t)(ob + cidx) * KTOT + k0 + lk];
        }
        __syncthreads();
#pragma unroll
        for (int kk = 0; kk < KT; kk++) {
            float av[4], wv[4];
#pragma unroll
            for (int i = 0; i < 4; i++) av[i] = As[kk][ty * 4 + i];
#pragma unroll
            for (int j = 0; j < 4; j++) wv[j] = Ws[kk][tx * 4 + j];
#pragma unroll
            for (int i = 0; i < 4; i++)
#pragma unroll
                for (int j = 0; j < 4; j++)
                    acc[i][j] = fmaf(av[i], wv[j], acc[i][j]);
        }
        __syncthreads();
    }

    // epilogue: bias + float4 stores
#pragma unroll
    for (int i = 0; i < 4; i++) {
        const size_t p = (size_t)(pb + ty * 4 + i);
        const int o = ob + tx * 4;
        float4 v;
        v.x = acc[i][0] + bias[o + 0];
        v.y = acc[i][1] + bias[o + 1];
        v.z = acc[i][2] + bias[o + 2];
        v.w = acc[i][3] + bias[o + 3];
        *reinterpret_cast<float4*>(&Cout[p * OC + o]) = v;
    }
}

// ---------------------------------------------------------------------------
// Per-channel sum / sumsq over points. X: [P, CH]; stats: [2*CH] (sum, sumsq)
// grid: (CH/64, rowBlocks); block 256 = 64 channels x 4 row-lanes
template <int CH>
__global__ __launch_bounds__(256) void stats_kernel(
    const float* __restrict__ X, float* __restrict__ stats, int rowsPerBlock) {
    const int cl = threadIdx.x & 63;
    const int c = blockIdx.x * 64 + cl;
    const int rl = threadIdx.x >> 6;
    const int r0 = blockIdx.y * rowsPerBlock;

    float s = 0.f, s2 = 0.f;
    for (int r = r0 + rl; r < r0 + rowsPerBlock; r += 4) {
        const float v = X[(size_t)r * CH + c];
        s += v;
        s2 = fmaf(v, v, s2);
    }
    __shared__ float ls[4][64], lq[4][64];
    ls[rl][cl] = s;
    lq[rl][cl] = s2;
    __syncthreads();
    if (rl == 0) {
        s  = ls[0][cl] + ls[1][cl] + ls[2][cl] + ls[3][cl];
        s2 = lq[0][cl] + lq[1][cl] + lq[2][cl] + lq[3][cl];
        atomicAdd(&stats[c], s);
        atomicAdd(&stats[CH + c], s2);
    }
}

// ---------------------------------------------------------------------------
// stats -> per-channel affine (a, b):  bn(v) = a*v + b
__global__ void finalize_kernel(const float* __restrict__ stats,
                                const float* __restrict__ g,
                                const float* __restrict__ be,
                                float* __restrict__ act, int CH, float invP) {
    const int c = blockIdx.x * blockDim.x + threadIdx.x;
    if (c < CH) {
        const float mean = stats[c] * invP;
        const float var = stats[CH + c] * invP - mean * mean;
        const float a = g[c] * rsqrtf(var + EPSBN);
        act[c] = a;
        act[CH + c] = be[c] - mean * a;
    }
}

// ---------------------------------------------------------------------------
// out[b,c,n] = a3[c]*o_pre[p,c] + b3[c] + relu(a1[c]*y_pre[p,c] + b1[c])
// with [p,C] -> [B,C,N] transpose via LDS tile.
__global__ __launch_bounds__(256) void final_kernel(
    const float* __restrict__ y_pre, const float* __restrict__ o_pre,
    const float* __restrict__ act1, const float* __restrict__ act3,
    float* __restrict__ out) {
    __shared__ float t[32][129];
    const int b = blockIdx.y;
    const int n0 = blockIdx.x * 32;
    const int tid = threadIdx.x;

    {
        const int cr = tid % 128;
        const int rq = tid / 128;
        const float a1 = act1[cr], b1 = act1[CC + cr];
        const float a3 = act3[cr], b3 = act3[CC + cr];
        for (int rl = rq; rl < 32; rl += 2) {
            const size_t p = (size_t)b * NN + n0 + rl;
            const float yv = y_pre[p * CC + cr];
            const float ov = o_pre[p * CC + cr];
            t[rl][cr] = fmaf(a3, ov, b3) + fmaxf(fmaf(a1, yv, b1), 0.f);
        }
    }
    __syncthreads();
    {
        const int tn = tid % 32;
        const int cq = tid / 32;
        for (int c = cq; c < CC; c += 8)
            out[((size_t)b * CC + c) * NN + n0 + tn] = t[tn][c];
    }
}

// ---------------------------------------------------------------------------
extern "C" void kernel_launch(void* const* d_in, const int* in_sizes, int n_in,
                              void* d_out, int out_size, void* d_ws, size_t ws_size,
                              hipStream_t stream) {
    const float* x     = (const float*)d_in[0];
    const int*   ei    = (const int*)d_in[1];
    const float* w_mr  = (const float*)d_in[2];
    const float* b_mr  = (const float*)d_in[3];
    const float* g_mr  = (const float*)d_in[4];
    const float* be_mr = (const float*)d_in[5];
    const float* w1    = (const float*)d_in[6];
    const float* b1    = (const float*)d_in[7];
    const float* g1    = (const float*)d_in[8];
    const float* be1   = (const float*)d_in[9];
    const float* w2    = (const float*)d_in[10];
    const float* b2    = (const float*)d_in[11];
    const float* g2    = (const float*)d_in[12];
    const float* be2   = (const float*)d_in[13];
    float* out = (float*)d_out;

    // workspace layout (floats); regions reused across dead phases:
    //   region0 (P*C):   xT      -> y_pre   (xT dead after gather)
    //   region1 (P*2C):  featT   -> o_pre   (featT dead after gemm1)
    //   region2 (P*H):   h_pre
    //   stats/act:       3*2*CH sums + 3*2*CH affine params
    float* ws = (float*)d_ws;
    float* xT    = ws;                                    // P*C    = 8388608
    float* y_pre = xT;
    float* featT = ws + (size_t)PP * CC;                  // P*2C   = 16777216
    float* o_pre = featT;
    float* h_pre = featT + (size_t)PP * TWO_C;            // P*H    = 33554432
    float* stats = h_pre + (size_t)PP * HH;
    float* stats1 = stats;          // 2*128
    float* stats2 = stats + 256;    // 2*512
    float* stats3 = stats + 1280;   // 2*128
    float* act1   = stats + 1536;   // 2*128
    float* act2   = stats + 1792;   // 2*512
    float* act3   = stats + 2816;   // 2*128

    const float invP = 1.0f / (float)PP;

    hipMemsetAsync(stats, 0, 1536 * sizeof(float), stream);

    transpose_kernel<<<dim3(NN / 32, BB), 256, 0, stream>>>(x, xT);
    gather_kernel<<<PP / 2, 256, 0, stream>>>(xT, ei, (float2*)featT);

    // GEMM1: feat[P,2C] @ w_mr^T -> y_pre[P,C]
    gemm_kernel<TWO_C, false><<<dim3(PP / 64, CC / 64), 256, 0, stream>>>(
        featT, w_mr, b_mr, act1, y_pre, CC);
    stats_kernel<CC><<<dim3(CC / 64, 256), 256, 0, stream>>>(y_pre, stats1, PP / 256);
    finalize_kernel<<<1, CC, 0, stream>>>(stats1, g_mr, be_mr, act1, CC, invP);

    // GEMM2: relu(bn1(y_pre))[P,C] @ w1^T -> h_pre[P,H]
    gemm_kernel<CC, true><<<dim3(PP / 64, HH / 64), 256, 0, stream>>>(
        y_pre, w1, b1, act1, h_pre, HH);
    stats_kernel<HH><<<dim3(HH / 64, 256), 256, 0, stream>>>(h_pre, stats2, PP / 256);
    finalize_kernel<<<1, HH, 0, stream>>>(stats2, g1, be1, act2, HH, invP);

    // GEMM3: relu(bn2(h_pre))[P,H] @ w2^T -> o_pre[P,C]
    gemm_kernel<HH, true><<<dim3(PP / 64, CC / 64), 256, 0, stream>>>(
        h_pre, w2, b2, act2, o_pre, CC);
    stats_kernel<CC><<<dim3(CC / 64, 256), 256, 0, stream>>>(o_pre, stats3, PP / 256);
    finalize_kernel<<<1, CC, 0, stream>>>(stats3, g2, be2, act3, CC, invP);

    // out = bn3(o_pre) + relu(bn1(y_pre)), transposed back to [B,C,N]
    final_kernel<<<dim3(NN / 32, BB), 256, 0, stream>>>(y_pre, o_pre, act1, act3, out);
}

// Round 2
// 171.083 us; speedup vs baseline: 3.6169x; 3.6169x over previous
//
#include <hip/hip_runtime.h>
#include <hip/hip_bf16.h>
#include <cstddef>
#include <cstdint>

// Problem constants: B=2, C=128, N=32768, K=9, H=512
#define BB 2
#define CC 128
#define NN 32768
#define KNBR 9
#define HH 512
#define PP (BB * NN)          // 65536 points
#define TWO_C 256
#define EPSBN 1e-5f

typedef __attribute__((ext_vector_type(4))) float f32x4;
typedef __attribute__((ext_vector_type(8))) short s16x8;
typedef __attribute__((ext_vector_type(4))) unsigned int u32x4;

__device__ __forceinline__ float bf2f(unsigned int u) {
    return __uint_as_float(u << 16);
}
__device__ __forceinline__ unsigned short f2bf(float f) {
    unsigned int u = __float_as_uint(f);
    u += 0x7fffu + ((u >> 16) & 1u);   // RNE
    return (unsigned short)(u >> 16);
}

// ---------------------------------------------------------------------------
// x [B, C, N] fp32 -> xT [B*N, C] bf16
__global__ __launch_bounds__(256) void transpose_kernel(
    const float* __restrict__ x, unsigned short* __restrict__ xT) {
    __shared__ float t[32][129];
    const int b = blockIdx.y;
    const int n0 = blockIdx.x * 32;
    const int tid = threadIdx.x;
    {
        const int tn = tid % 32;
        const int cq = tid / 32;
        for (int c = cq; c < CC; c += 8)
            t[tn][c] = x[((size_t)b * CC + c) * NN + n0 + tn];
    }
    __syncthreads();
    {
        const int ct = tid % 128;
        const int nq = tid / 128;
        for (int nl = nq; nl < 32; nl += 2)
            xT[((size_t)b * NN + n0 + nl) * CC + ct] = f2bf(t[nl][ct]);
    }
}

// ---------------------------------------------------------------------------
// Gather + max-relative; featT[p][2c]=x[p][c], featT[p][2c+1]=max_k(x_j-x_i).
// 4 points per block; 64 lanes per point; each lane owns channels 2l, 2l+1.
__global__ __launch_bounds__(256) void gather_kernel(
    const unsigned short* __restrict__ xT, const int* __restrict__ ei,
    unsigned short* __restrict__ featT) {
    const int pt = blockIdx.x * 4 + (threadIdx.x >> 6);
    const int lane = threadIdx.x & 63;
    const int b = pt >> 15;
    const int n = pt & (NN - 1);
    const unsigned short* xb = xT + (size_t)b * NN * CC;
    const int* e0 = ei + ((size_t)b * NN + n) * KNBR;            // edge_index[0]: x_j
    const int* e1 = ei + ((size_t)(BB + b) * NN + n) * KNBR;     // edge_index[1]: x_i

    const unsigned int xv = *(const unsigned int*)(xb + (size_t)n * CC + lane * 2);
    float m0 = -INFINITY, m1 = -INFINITY;
#pragma unroll
    for (int k = 0; k < KNBR; k++) {
        const int j0 = e0[k], j1 = e1[k];
        const unsigned int va = *(const unsigned int*)(xb + (size_t)j0 * CC + lane * 2);
        const unsigned int vb = *(const unsigned int*)(xb + (size_t)j1 * CC + lane * 2);
        m0 = fmaxf(m0, bf2f(va & 0xffffu) - bf2f(vb & 0xffffu));
        m1 = fmaxf(m1, bf2f(va >> 16) - bf2f(vb >> 16));
    }
    ushort4 o;
    o.x = (unsigned short)(xv & 0xffffu);
    o.y = f2bf(m0);
    o.z = (unsigned short)(xv >> 16);
    o.w = f2bf(m1);
    *(ushort4*)(featT + (size_t)pt * TWO_C + lane * 4) = o;
}

// ---------------------------------------------------------------------------
// fp32 weights -> bf16 (w_mr: 32768, w1: 65536, w2: 65536)
__global__ __launch_bounds__(256) void wconv_kernel(
    const float* __restrict__ w_mr, const float* __restrict__ w1,
    const float* __restrict__ w2, unsigned short* __restrict__ o_mr,
    unsigned short* __restrict__ o1, unsigned short* __restrict__ o2) {
    const int i = blockIdx.x * 256 + threadIdx.x;
    if (i < CC * TWO_C) o_mr[i] = f2bf(w_mr[i]);
    o1[i] = f2bf(w1[i]);
    o2[i] = f2bf(w2[i]);
}

// ---------------------------------------------------------------------------
// bf16 MFMA GEMM: Cout[p,o] = sum_k actA(A[p,k]) * W[o,k] + bias[o]
//   actA(v) = ACT ? bf16(relu(a[k]*v + b[k])) : v
// Tile 128x128, BK=64, 256 threads = 4 waves (2x2 of 64x64), 16x16x32 MFMA.
// LDS tiles XOR-swizzled (byte ^= (row&7)<<4) -> 2-way-max bank aliasing.
// Per-channel sum/sumsq of (acc+bias) fused into epilogue -> stats[2*OC].
template <int KTOT, int OC, bool ACT>
__global__ __launch_bounds__(256) void mgemm_kernel(
    const unsigned short* __restrict__ A,
    const unsigned short* __restrict__ W,
    const float* __restrict__ bias,
    const float* __restrict__ act,      // [2*KTOT]: a then b
    unsigned short* __restrict__ Cout,
    float* __restrict__ stats) {
    __shared__ __align__(16) unsigned short As[128 * 64];
    __shared__ __align__(16) unsigned short Bs[128 * 64];
    __shared__ float bsA[256];
    __shared__ float bsB[256];

    const int tid = threadIdx.x;
    const int pb = blockIdx.x * 128;
    const int ob = blockIdx.y * 128;
    const int w = tid >> 6;
    const int wr = w >> 1, wc = w & 1;
    const int lane = tid & 63;
    const int lm = lane & 15, lg = lane >> 4;

    f32x4 acc[4][4] = {};

    for (int k0 = 0; k0 < KTOT; k0 += 64) {
        // ---- stage A and W tiles (reg-staged, swizzled ds_write) ----
#pragma unroll
        for (int i = 0; i < 4; i++) {
            const int idx = tid + i * 256;       // 0..1023
            const int row = idx >> 3;            // 0..127
            const int kb = (idx & 7) * 16;       // byte in 128B row
            const int sw = kb ^ ((row & 7) << 4);
            {
                const char* src = (const char*)(A + (size_t)(pb + row) * KTOT + k0) + kb;
                if (!ACT) {
                    const u32x4 v = *(const u32x4*)src;
                    *(u32x4*)((char*)As + row * 128 + sw) = v;
                } else {
                    const s16x8 v = *(const s16x8*)src;
                    const int ke = k0 + (kb >> 1);
                    const f32x4 sa0 = *(const f32x4*)(act + ke);
                    const f32x4 sa1 = *(const f32x4*)(act + ke + 4);
                    const f32x4 sb0 = *(const f32x4*)(act + KTOT + ke);
                    const f32x4 sb1 = *(const f32x4*)(act + KTOT + ke + 4);
                    s16x8 r;
#pragma unroll
                    for (int j = 0; j < 4; j++) {
                        const float f = bf2f((unsigned short)v[j]);
                        r[j] = (short)f2bf(fmaxf(fmaf(sa0[j], f, sb0[j]), 0.f));
                    }
#pragma unroll
                    for (int j = 0; j < 4; j++) {
                        const float f = bf2f((unsigned short)v[4 + j]);
                        r[4 + j] = (short)f2bf(fmaxf(fmaf(sa1[j], f, sb1[j]), 0.f));
                    }
                    *(s16x8*)((char*)As + row * 128 + sw) = r;
                }
            }
            {
                const char* src = (const char*)(W + (size_t)(ob + row) * KTOT + k0) + kb;
                const u32x4 v = *(const u32x4*)src;
                *(u32x4*)((char*)Bs + row * 128 + sw) = v;
            }
        }
        __syncthreads();
        // ---- MFMA on the tile ----
#pragma unroll
        for (int kk = 0; kk < 2; kk++) {
            s16x8 aF[4], bF[4];
            const int kbyte = kk * 64 + lg * 16;
#pragma unroll
            for (int m = 0; m < 4; m++) {
                const int r = wr * 64 + m * 16 + lm;
                aF[m] = *(const s16x8*)((const char*)As + r * 128 + (kbyte ^ ((r & 7) << 4)));
            }
#pragma unroll
            for (int n = 0; n < 4; n++) {
                const int c = wc * 64 + n * 16 + lm;
                bF[n] = *(const s16x8*)((const char*)Bs + c * 128 + (kbyte ^ ((c & 7) << 4)));
            }
#pragma unroll
            for (int m = 0; m < 4; m++)
#pragma unroll
                for (int n = 0; n < 4; n++)
                    acc[m][n] = __builtin_amdgcn_mfma_f32_16x16x32_bf16(
                        aF[m], bF[n], acc[m][n], 0, 0, 0);
        }
        __syncthreads();
    }

    // ---- epilogue: bias, bf16 store, fused per-channel stats ----
    float sA[4] = {0.f, 0.f, 0.f, 0.f};
    float sB[4] = {0.f, 0.f, 0.f, 0.f};
#pragma unroll
    for (int n = 0; n < 4; n++) {
        const int o = ob + wc * 64 + n * 16 + lm;
        const float bo = bias[o];
#pragma unroll
        for (int m = 0; m < 4; m++) {
            const size_t p = (size_t)pb + wr * 64 + m * 16 + lg * 4;
#pragma unroll
            for (int j = 0; j < 4; j++) {
                const float h = acc[m][n][j] + bo;
                Cout[(p + j) * OC + o] = f2bf(h);
                sA[n] += h;
                sB[n] = fmaf(h, h, sB[n]);
            }
        }
    }
#pragma unroll
    for (int n = 0; n < 4; n++) {
        float a = sA[n], q = sB[n];
        a += __shfl_xor(a, 16); a += __shfl_xor(a, 32);
        q += __shfl_xor(q, 16); q += __shfl_xor(q, 32);
        if (lg == 0) {
            bsA[wr * 128 + wc * 64 + n * 16 + lm] = a;
            bsB[wr * 128 + wc * 64 + n * 16 + lm] = q;
        }
    }
    __syncthreads();
    if (tid < 128) {
        atomicAdd(&stats[ob + tid], bsA[tid] + bsA[128 + tid]);
        atomicAdd(&stats[OC + ob + tid], bsB[tid] + bsB[128 + tid]);
    }
}

// ---------------------------------------------------------------------------
// stats -> per-channel affine (a, b): bn(v) = a*v + b
__global__ void finalize_kernel(const float* __restrict__ stats,
                                const float* __restrict__ g,
                                const float* __restrict__ be,
                                float* __restrict__ act, int CH, float invP) {
    const int c = blockIdx.x * blockDim.x + threadIdx.x;
    if (c < CH) {
        const float mean = stats[c] * invP;
        const float var = stats[CH + c] * invP - mean * mean;
        const float a = g[c] * rsqrtf(var + EPSBN);
        act[c] = a;
        act[CH + c] = be[c] - mean * a;
    }
}

// ---------------------------------------------------------------------------
// out[b,c,n] = a3[c]*o[p,c] + b3[c] + relu(a1[c]*y[p,c] + b1[c]); [p,C]->[B,C,N]
__global__ __launch_bounds__(256) void final_kernel(
    const unsigned short* __restrict__ y_bf, const unsigned short* __restrict__ o_bf,
    const float* __restrict__ act1, const float* __restrict__ act3,
    float* __restrict__ out) {
    __shared__ float t[32][129];
    const int b = blockIdx.y;
    const int n0 = blockIdx.x * 32;
    const int tid = threadIdx.x;
    {
        const int lane = tid & 63;
        const int rq = tid >> 6;
        const int c0 = lane * 2;
        const float a1x = act1[c0], a1y = act1[c0 + 1];
        const float b1x = act1[CC + c0], b1y = act1[CC + c0 + 1];
        const float a3x = act3[c0], a3y = act3[c0 + 1];
        const float b3x = act3[CC + c0], b3y = act3[CC + c0 + 1];
        for (int rl = rq; rl < 32; rl += 4) {
            const size_t p = (size_t)b * NN + n0 + rl;
            const unsigned int yv = *(const unsigned int*)(y_bf + p * CC + c0);
            const unsigned int ov = *(const unsigned int*)(o_bf + p * CC + c0);
            t[rl][c0]     = fmaf(a3x, bf2f(ov & 0xffffu), b3x) +
                            fmaxf(fmaf(a1x, bf2f(yv & 0xffffu), b1x), 0.f);
            t[rl][c0 + 1] = fmaf(a3y, bf2f(ov >> 16), b3y) +
                            fmaxf(fmaf(a1y, bf2f(yv >> 16), b1y), 0.f);
        }
    }
    __syncthreads();
    {
        const int tn = tid % 32;
        const int cq = tid / 32;
        for (int c = cq; c < CC; c += 8)
            out[((size_t)b * CC + c) * NN + n0 + tn] = t[tn][c];
    }
}

// ---------------------------------------------------------------------------
extern "C" void kernel_launch(void* const* d_in, const int* in_sizes, int n_in,
                              void* d_out, int out_size, void* d_ws, size_t ws_size,
                              hipStream_t stream) {
    const float* x     = (const float*)d_in[0];
    const int*   ei    = (const int*)d_in[1];
    const float* w_mr  = (const float*)d_in[2];
    const float* b_mr  = (const float*)d_in[3];
    const float* g_mr  = (const float*)d_in[4];
    const float* be_mr = (const float*)d_in[5];
    const float* w1    = (const float*)d_in[6];
    const float* b1    = (const float*)d_in[7];
    const float* g1    = (const float*)d_in[8];
    const float* be1   = (const float*)d_in[9];
    const float* w2    = (const float*)d_in[10];
    const float* b2    = (const float*)d_in[11];
    const float* g2    = (const float*)d_in[12];
    const float* be2   = (const float*)d_in[13];
    float* out = (float*)d_out;

    // workspace layout (bytes)
    char* ws = (char*)d_ws;
    unsigned short* xT    = (unsigned short*)(ws + 0);           // P*C*2   = 16 MB
    unsigned short* featT = (unsigned short*)(ws + 16777216);    // P*2C*2  = 32 MB
    unsigned short* y_bf  = (unsigned short*)(ws + 50331648);    // P*C*2   = 16 MB
    unsigned short* h_bf  = (unsigned short*)(ws + 67108864);    // P*H*2   = 64 MB
    unsigned short* o_bf  = (unsigned short*)(ws + 134217728);   // P*C*2   = 16 MB
    unsigned short* wmr_b = (unsigned short*)(ws + 150994944);   // 64 KB
    unsigned short* w1_b  = (unsigned short*)(ws + 151060480);   // 128 KB
    unsigned short* w2_b  = (unsigned short*)(ws + 151191552);   // 128 KB
    float* stats1 = (float*)(ws + 151322624);                    // 2*128
    float* stats2 = (float*)(ws + 151323648);                    // 2*512
    float* stats3 = (float*)(ws + 151327744);                    // 2*128
    float* act1   = (float*)(ws + 151328768);                    // 2*128
    float* act2   = (float*)(ws + 151329792);                    // 2*512
    float* act3   = (float*)(ws + 151333888);                    // 2*128

    const float invP = 1.0f / (float)PP;

    hipMemsetAsync(stats1, 0, 6144, stream);   // zero all three stats arrays

    transpose_kernel<<<dim3(NN / 32, BB), 256, 0, stream>>>(x, xT);
    gather_kernel<<<PP / 4, 256, 0, stream>>>(xT, ei, featT);
    wconv_kernel<<<256, 256, 0, stream>>>(w_mr, w1, w2, wmr_b, w1_b, w2_b);

    // GEMM1: feat[P,256] @ w_mr^T -> y[P,128]  (+ fused stats1)
    mgemm_kernel<TWO_C, CC, false><<<dim3(PP / 128, 1), 256, 0, stream>>>(
        featT, wmr_b, b_mr, act1, y_bf, stats1);
    finalize_kernel<<<1, CC, 0, stream>>>(stats1, g_mr, be_mr, act1, CC, invP);

    // GEMM2: relu(bn1(y))[P,128] @ w1^T -> h[P,512]  (+ fused stats2)
    mgemm_kernel<CC, HH, true><<<dim3(PP / 128, HH / 128), 256, 0, stream>>>(
        y_bf, w1_b, b1, act1, h_bf, stats2);
    finalize_kernel<<<1, HH, 0, stream>>>(stats2, g1, be1, act2, HH, invP);

    // GEMM3: relu(bn2(h))[P,512] @ w2^T -> o[P,128]  (+ fused stats3)
    mgemm_kernel<HH, CC, true><<<dim3(PP / 128, 1), 256, 0, stream>>>(
        h_bf, w2_b, b2, act2, o_bf, stats3);
    finalize_kernel<<<1, CC, 0, stream>>>(stats3, g2, be2, act3, CC, invP);

    // out = bn3(o) + relu(bn1(y)), back to [B,C,N]
    final_kernel<<<dim3(NN / 32, BB), 256, 0, stream>>>(y_bf, o_bf, act1, act3, out);
}